// Round 4
// baseline (475.691 us; speedup 1.0000x reference)
//
#include <hip/hip_runtime.h>
#include <math.h>
#include <stdint.h>

#define NTOK   16384
#define DIM    4096
#define NEXP   256
#define TOPKG  4
#define TOPK   8
#define NSPLIT 4
#define KCHUNK (DIM / NSPLIT)   // 1024
#define BM     256
#define BK     32
#define NSTEPS (KCHUNK / BK)    // 32

typedef float v4f   __attribute__((ext_vector_type(4)));
typedef short short8 __attribute__((ext_vector_type(8)));

__device__ inline unsigned short f2bf(float x) {           // round-to-nearest-even
    unsigned u = __float_as_uint(x);
    return (unsigned short)((u + 0x7fffu + ((u >> 16) & 1u)) >> 16);
}
__device__ inline float bf2f(unsigned short h) {
    return __uint_as_float(((unsigned)h) << 16);
}
// 4-slot XOR swizzle within a 64B row (involution; verified R2: conflicts=0)
__device__ inline int swz4(int row, int slot) { return slot ^ ((row >> 1) & 3); }

// ---- W fp32 -> Wp[z][step][32KB]: contiguous, pre-swizzled, gl_lds-ready ----
// Per (z,s) block of 16384 shorts: [0..8191]=Bh rows [256][32], [8192..]=Bl.
// LDS slot s' of row e holds source k-slot swz4(e,s') (involution with reader).
__global__ __launch_bounds__(256) void wprep(const float* __restrict__ W,
                                             unsigned short* __restrict__ Wp) {
    int u  = blockIdx.x * 256 + threadIdx.x;   // 0..262143 (one 16B chunk each)
    int zs = u >> 11;                          // z*32 + s
    int c  = u & 2047;
    int z  = zs >> 5, s = zs & 31;
    int half = c >> 10;                        // 0: hi, 1: lo
    int cc = c & 1023;
    int e  = cc >> 2, sl = cc & 3;
    int sig = swz4(e, sl);
    const float* src = W + (size_t)e * DIM + z * KCHUNK + s * BK + sig * 8;
    float4 v0 = *(const float4*)src;
    float4 v1 = *(const float4*)(src + 4);
    float xf[8] = {v0.x, v0.y, v0.z, v0.w, v1.x, v1.y, v1.z, v1.w};
    short8 out;
#pragma unroll
    for (int j = 0; j < 8; ++j) {
        unsigned short h = f2bf(xf[j]);
        out[j] = half ? (short)f2bf(xf[j] - bf2f(h)) : (short)h;
    }
    *(short8*)(Wp + (size_t)u * 8) = out;
}

// ---- GEMM: P[z][t][e] = sum_{k in chunk z} X[t,k] W[e,k], bf16x2 3-pass MFMA ----
// 2-phase dbuf, ONE __syncthreads/step. B staging is now a CONTIGUOUS 32KB
// stream per step from Wp (no 8KB-strided gather), and blocks are mapped so
// each XCD serves exactly one z -> its 1MB Wp slice is L2-resident. Prefetch
// (issued at step top) gets the full MFMA phase (~4k cyc) of flight before the
// end-of-step drain.
__global__ __launch_bounds__(512, 2) void gate_gemm(const float* __restrict__ X,
                                                    const unsigned short* __restrict__ Wp,
                                                    float* __restrict__ P) {
    __shared__ __align__(16) unsigned short Bbuf[2][NEXP * BK * 2];  // 2 x 32 KB
    __shared__ __align__(16) unsigned short Ah[2][BM * BK];          // 2 x 16 KB
    __shared__ __align__(16) unsigned short Al[2][BM * BK];          // -> 128 KB

    const int t = threadIdx.x;             // 0..511
    // z-per-XCD mapping: XCD = b%8 (dispatch round-robin); z=(b%8)>>1 so each
    // XCD touches ONE z's Wp slice (1MB, L2-resident). x = 2*(b>>3)+(b&1).
    const int b  = blockIdx.x;             // 0..255
    const int z  = (b & 7) >> 1;
    const int bm = (2 * (b >> 3) + (b & 1)) * BM;

    const int l  = t & 63;
    const int w  = t >> 6;                 // 0..7
    const int wr = w >> 2;                 // 0..1: row half (128 tokens)
    const int wc = w & 3;                  // 0..3: col quarter (64 experts)
    const int lm = l & 15;
    const int lq = l >> 4;                 // 16B k-slot (0..3)

    const unsigned short* wz = Wp + (size_t)z * NSTEPS * (NEXP * BK * 2);

    // A staging: thread t -> row t>>1 (0..255), k-half (t&1)*16
    const int ar = t >> 1;
    const float* xrow = X + (size_t)(bm + ar) * DIM + z * KCHUNK + (t & 1) * 16;

    v4f acc[8][4] = {};

    // ---- prologue: stage step 0 into buffer 0 ----
    {
        float4 xv0[4];
#pragma unroll
        for (int i = 0; i < 4; ++i) xv0[i] = *(const float4*)(xrow + i * 4);
#pragma unroll
        for (int j = 0; j < 4; ++j) {
            int flat = j * 512 + t;
            __builtin_amdgcn_global_load_lds(
                (const __attribute__((address_space(1))) unsigned int*)(wz + flat * 8),
                (__attribute__((address_space(3))) unsigned int*)&Bbuf[0][flat * 8], 16, 0, 0);
        }
#pragma unroll
        for (int i = 0; i < 4; ++i) {
            ushort4 h, lo;
            h.x = f2bf(xv0[i].x); lo.x = f2bf(xv0[i].x - bf2f(h.x));
            h.y = f2bf(xv0[i].y); lo.y = f2bf(xv0[i].y - bf2f(h.y));
            h.z = f2bf(xv0[i].z); lo.z = f2bf(xv0[i].z - bf2f(h.z));
            h.w = f2bf(xv0[i].w); lo.w = f2bf(xv0[i].w - bf2f(h.w));
            int j = (t & 1) * 4 + i;
            int idx = ar * BK + swz4(ar, j >> 1) * 8 + (j & 1) * 4;
            *(ushort4*)&Ah[0][idx] = h;
            *(ushort4*)&Al[0][idx] = lo;
        }
        __syncthreads();   // full drain: step 0 visible
    }

    int cur = 0;
    for (int s = 0; s < NSTEPS; ++s) {
        const int nxt = cur ^ 1;
        const bool pf = (s + 1 < NSTEPS);

        // ---- issue prefetch of step s+1 (no waits) ----
        float4 xv[4];
        if (pf) {
#pragma unroll
            for (int i = 0; i < 4; ++i) xv[i] = *(const float4*)(xrow + (s + 1) * BK + i * 4);
            const unsigned short* wsrc = wz + (size_t)(s + 1) * (NEXP * BK * 2);
#pragma unroll
            for (int j = 0; j < 4; ++j) {
                int flat = j * 512 + t;
                __builtin_amdgcn_global_load_lds(
                    (const __attribute__((address_space(1))) unsigned int*)(wsrc + flat * 8),
                    (__attribute__((address_space(3))) unsigned int*)&Bbuf[nxt][flat * 8], 16, 0, 0);
            }
        }
        __builtin_amdgcn_sched_barrier(0);   // pin issue above compute

        // ---- compute step s from buffer cur ----
        short8 bh[4], bl[4];
#pragma unroll
        for (int c = 0; c < 4; ++c) {
            int e = wc * 64 + c * 16 + lm;
            bh[c] = *(const short8*)&Bbuf[cur][e * BK + swz4(e, lq) * 8];
            bl[c] = *(const short8*)&Bbuf[cur][NEXP * BK + e * BK + swz4(e, lq) * 8];
        }
        __builtin_amdgcn_s_setprio(1);
#pragma unroll
        for (int r = 0; r < 8; ++r) {
            int m = wr * 128 + r * 16 + lm;
            short8 ah = *(const short8*)&Ah[cur][m * BK + swz4(m, lq) * 8];
            short8 al = *(const short8*)&Al[cur][m * BK + swz4(m, lq) * 8];
#pragma unroll
            for (int c = 0; c < 4; ++c) {
                acc[r][c] = __builtin_amdgcn_mfma_f32_16x16x32_bf16(ah, bh[c], acc[r][c], 0, 0, 0);
                acc[r][c] = __builtin_amdgcn_mfma_f32_16x16x32_bf16(ah, bl[c], acc[r][c], 0, 0, 0);
                acc[r][c] = __builtin_amdgcn_mfma_f32_16x16x32_bf16(al, bh[c], acc[r][c], 0, 0, 0);
            }
        }
        __builtin_amdgcn_s_setprio(0);
        __builtin_amdgcn_sched_barrier(0);   // keep xv-dependent convert below MFMAs

        // ---- convert + write A(s+1) into buffer nxt ----
        if (pf) {
#pragma unroll
            for (int i = 0; i < 4; ++i) {
                ushort4 h, lo;
                h.x = f2bf(xv[i].x); lo.x = f2bf(xv[i].x - bf2f(h.x));
                h.y = f2bf(xv[i].y); lo.y = f2bf(xv[i].y - bf2f(h.y));
                h.z = f2bf(xv[i].z); lo.z = f2bf(xv[i].z - bf2f(h.z));
                h.w = f2bf(xv[i].w); lo.w = f2bf(xv[i].w - bf2f(h.w));
                int j = (t & 1) * 4 + i;
                int idx = ar * BK + swz4(ar, j >> 1) * 8 + (j & 1) * 4;
                *(ushort4*)&Ah[nxt][idx] = h;
                *(ushort4*)&Al[nxt][idx] = lo;
            }
        }

        __syncthreads();   // single drain/step: publishes buffers for s+1
        cur = nxt;
    }

    // epilogue: C/D layout col=lane&15, row=lq*4+reg (verified m89/m91)
    // NT stores: P is streamed, keep it out of L2 (protect Wp residency)
    float* Pb = P + ((size_t)z * NTOK + bm) * NEXP;
#pragma unroll
    for (int r = 0; r < 8; ++r)
#pragma unroll
        for (int c = 0; c < 4; ++c)
#pragma unroll
            for (int g = 0; g < 4; ++g)
                __builtin_nontemporal_store(acc[r][c][g],
                    &Pb[(size_t)(wr * 128 + r * 16 + lq * 4 + g) * NEXP + wc * 64 + c * 16 + lm]);
}

// ---- fused reduce (4 partials, fixed order) + routing: one wave per token ----
__global__ __launch_bounds__(256) void gate_route(const float* __restrict__ P,
                                                  float* __restrict__ outw,
                                                  float* __restrict__ outi) {
    const int lane = threadIdx.x & 63;
    const int tok  = (blockIdx.x * blockDim.x + threadIdx.x) >> 6;
    if (tok >= NTOK) return;

    float l[4] = {0.f, 0.f, 0.f, 0.f};
#pragma unroll
    for (int z = 0; z < NSPLIT; ++z) {   // fixed order: deterministic across runs
        float4 v = *(const float4*)(P + ((size_t)z * NTOK + tok) * NEXP + lane * 4);
        l[0] += v.x; l[1] += v.y; l[2] += v.z; l[3] += v.w;
    }

    float lmax = fmaxf(fmaxf(l[0], l[1]), fmaxf(l[2], l[3]));
    float m = lmax;
#pragma unroll
    for (int o = 32; o; o >>= 1) m = fmaxf(m, __shfl_xor(m, o));

    float s = __expf(l[0] - m) + __expf(l[1] - m) + __expf(l[2] - m) + __expf(l[3] - m);
#pragma unroll
    for (int o = 32; o; o >>= 1) s += __shfl_xor(s, o);

    float gm = lmax;
#pragma unroll
    for (int o = 4; o; o >>= 1) gm = fmaxf(gm, __shfl_xor(gm, o));

    const int g = lane >> 3;
    int rank = 0;
#pragma unroll
    for (int gg = 0; gg < 8; ++gg) {
        float vg = __shfl(gm, gg * 8);
        rank += (vg > gm) || (vg == gm && gg < g);
    }
    const bool allowed = rank < TOPKG;

    float mv[4];
#pragma unroll
    for (int j = 0; j < 4; ++j) mv[j] = allowed ? l[j] : -INFINITY;

    float wsel = 0.0f;
    int   isel = 0;

    for (int k = 0; k < TOPK; ++k) {
        float bv = mv[0];
        int   bi = lane * 4;
        if (mv[1] > bv) { bv = mv[1]; bi = lane * 4 + 1; }
        if (mv[2] > bv) { bv = mv[2]; bi = lane * 4 + 2; }
        if (mv[3] > bv) { bv = mv[3]; bi = lane * 4 + 3; }
#pragma unroll
        for (int o = 32; o; o >>= 1) {
            float ov = __shfl_xor(bv, o);
            int   oi = __shfl_xor(bi, o);
            if (ov > bv || (ov == bv && oi < bi)) { bv = ov; bi = oi; }
        }
        if (lane == k) { wsel = __expf(bv - m) / s; isel = bi; }
        if ((bi >> 2) == lane) mv[bi & 3] = -INFINITY;
    }

    if (lane < TOPK) {
        outw[(size_t)tok * TOPK + lane] = wsel;
        outi[(size_t)tok * TOPK + lane] = (float)isel;
    }
}

extern "C" void kernel_launch(void* const* d_in, const int* in_sizes, int n_in,
                              void* d_out, int out_size, void* d_ws, size_t ws_size,
                              hipStream_t stream) {
    const float* x  = (const float*)d_in[0];   // [16384, 4096]
    const float* wt = (const float*)d_in[1];   // [256, 4096]

    // ws layout: partials [4][16384][256] f32 (64 MB) | Wp (4 MB)
    float* P = (float*)d_ws;
    unsigned short* Wp = (unsigned short*)((char*)d_ws + (size_t)NSPLIT * NTOK * NEXP * 4);

    float* outw = (float*)d_out;
    float* outi = (float*)d_out + (size_t)NTOK * TOPK;

    wprep<<<1024, 256, 0, stream>>>(wt, Wp);

    gate_gemm<<<256, 512, 0, stream>>>(x, Wp, P);   // 256 blocks, 1/CU, 8 waves

    gate_route<<<(NTOK * 64) / 256, 256, 0, stream>>>(P, outw, outi);
}